// Round 4
// baseline (923.621 us; speedup 1.0000x reference)
//
#include <hip/hip_runtime.h>

#define N_NODES 100000
#define N_EDGES 1600000
#define F_IN    512
#define HIDDEN  16
#define N_CLS   40

#define BSHIFT  7
#define BSIZE   128                                // nodes per bucket
#define NB      ((N_NODES + BSIZE - 1) / BSIZE)    // 782 buckets
#define NWGBIN  256
#define CHUNK   (N_EDGES / NWGBIN)                 // 6250 (exact)

static_assert(N_EDGES % NWGBIN == 0, "chunking must be exact");

// ---------------- zero bucket counters ----------------
__global__ void k_zero(int* __restrict__ p, int n) {
    int i = blockIdx.x * blockDim.x + threadIdx.x;
    if (i < n) p[i] = 0;
}

// ---------------- pass A: per-bucket edge counts ----------------
__global__ __launch_bounds__(256) void k_binc(const int* __restrict__ ei,
                                              int* __restrict__ bucketCnt) {
    __shared__ int h[NB];
    int t = threadIdx.x;
    for (int b = t; b < NB; b += 256) h[b] = 0;
    __syncthreads();
    int start = blockIdx.x * CHUNK, end = start + CHUNK;
    for (int e = start + t; e < end; e += 256)
        atomicAdd(&h[ei[N_EDGES + e] >> BSHIFT], 1);
    __syncthreads();
    for (int b = t; b < NB; b += 256)
        if (h[b]) atomicAdd(&bucketCnt[b], h[b]);
}

// ---------------- exclusive scan of 782 bucket counts ----------------
__global__ __launch_bounds__(1024) void k_bscan(const int* __restrict__ bucketCnt,
                                                int* __restrict__ boff,
                                                int* __restrict__ cur) {
    __shared__ int s[1024];
    int t = threadIdx.x;
    int v = (t < NB) ? bucketCnt[t] : 0;
    s[t] = v; __syncthreads();
    for (int o = 1; o < 1024; o <<= 1) {
        int add = (t >= o) ? s[t - o] : 0;
        __syncthreads();
        s[t] += add;
        __syncthreads();
    }
    if (t < NB) { int ex = s[t] - v; boff[t] = ex; cur[t] = ex; }
    if (t == 0) boff[NB] = N_EDGES;
}

// ---------------- pass B: place packed edges (r | lc<<17) ----------------
__global__ __launch_bounds__(256) void k_bfill(const int* __restrict__ ei,
                                               int* __restrict__ cur,
                                               int* __restrict__ binned) {
    __shared__ int lc[NB];
    int t = threadIdx.x;
    int start = blockIdx.x * CHUNK, end = start + CHUNK;
    for (int b = t; b < NB; b += 256) lc[b] = 0;
    __syncthreads();
    for (int e = start + t; e < end; e += 256)
        atomicAdd(&lc[ei[N_EDGES + e] >> BSHIFT], 1);
    __syncthreads();
    for (int b = t; b < NB; b += 256) {
        int c = lc[b];
        lc[b] = c ? atomicAdd(&cur[b], c) : 0;
    }
    __syncthreads();
    for (int e = start + t; e < end; e += 256) {
        int r = ei[e], c = ei[N_EDGES + e];
        int b = c >> BSHIFT;
        int pos = atomicAdd(&lc[b], 1);
        binned[pos] = r | ((c & (BSIZE - 1)) << 17);
    }
}

// ------ per-bucket counting sort: binned -> node-sorted csr + offsets/cnt/dis ----
__global__ __launch_bounds__(256) void k_csr(const int* __restrict__ boff,
                                             const int* __restrict__ binned,
                                             int* __restrict__ csr,
                                             int* __restrict__ offsets,
                                             int* __restrict__ cnt,
                                             float* __restrict__ dis) {
    __shared__ int h[BSIZE];      // per-local-node histogram
    __shared__ int sc[BSIZE];     // scan
    __shared__ int curL[BSIZE];   // local cursors (absolute csr positions)
    int t = threadIdx.x, b = blockIdx.x;
    if (t < BSIZE) h[t] = 0;
    __syncthreads();
    int s = boff[b], e = boff[b + 1];
    for (int i = s + t; i < e; i += 256)
        atomicAdd(&h[binned[i] >> 17], 1);
    __syncthreads();
    int v = (t < BSIZE) ? h[t] : 0;
    if (t < BSIZE) sc[t] = v;
    __syncthreads();
    for (int o = 1; o < BSIZE; o <<= 1) {
        int add = (t < BSIZE && t >= o) ? sc[t - o] : 0;
        __syncthreads();
        if (t < BSIZE) sc[t] += add;
        __syncthreads();
    }
    if (t < BSIZE) {
        int ex = s + sc[t] - v;           // absolute exclusive offset
        curL[t] = ex;
        int node = b * BSIZE + t;
        if (node < N_NODES) {
            offsets[node] = ex;
            cnt[node]     = v;
            dis[node]     = rsqrtf(1.0f + (float)v);
        }
    }
    __syncthreads();
    for (int i = s + t; i < e; i += 256) {
        int p = binned[i];
        int pos = atomicAdd(&curL[p >> 17], 1);
        csr[pos] = p & 0x1FFFF;
    }
}

// ---------------- layer-1 GEMM: h1s = (x @ W1) * dis ----------------
// 8 lanes per row, 2 rows per thread (stride 32), 64 rows / 256-thread WG.
// W in kq-major swizzled 32 KiB LDS (verified: 0 bank conflicts, round 3).
// v4: NO min-wave launch-bounds clamp (round 3's (256,4) forced VGPR 72->64
// and spilled: WRITE_SIZE 44->201 MB, +53 us). Prefetch DEPTH 2 with named
// registers + full unroll so all indices are compile-time (no scratch):
// tile i+2 issues while tile i computes -> ~2x256 VALU cyc per wave between
// issue and use; at >=4 waves/SIMD that exceeds the ~900-cyc HBM latency.
__global__ __launch_bounds__(256) void k_gemm1(
        const float* __restrict__ x, const float* __restrict__ W1,
        const float* __restrict__ dis, float* __restrict__ h1s) {
    __shared__ float sW[F_IN * HIDDEN];   // 8192 floats = 32 KiB exact
    for (int idx = threadIdx.x; idx < F_IN * HIDDEN; idx += 256) {
        int k = idx >> 4, j = idx & 15;
        int kq = k >> 2, kl = k & 3, jb = j >> 2, jl = j & 3;
        int pos = kq * 64 + ((kl ^ (kq & 1)) << 4)
                + ((((jb + (kq >> 1)) & 3)) << 2) + jl;
        sW[pos] = W1[idx];
    }
    __syncthreads();

    int t = threadIdx.x;
    int o = t & 7;                      // k-lane within the row octet
    int row0 = blockIdx.x * 64 + (t >> 3);
    int row1 = row0 + 32;
    bool ok0 = row0 < N_NODES, ok1 = row1 < N_NODES;
    const float* x0 = x + (size_t)row0 * F_IN;
    const float* x1 = x + (size_t)row1 * F_IN;
    float d0 = ok0 ? dis[row0] : 0.0f;   // hoist dependent loads
    float d1 = ok1 ? dis[row1] : 0.0f;

    // read-side swizzle constants
    const int klx = o & 1;              // xor on the kl slot
    const int js  = (o >> 1) & 3;       // jb rotation
    const int rof0 = ((0 + js) & 3) << 2;
    const int rof1 = ((1 + js) & 3) << 2;
    const int rof2 = ((2 + js) & 3) << 2;
    const int rof3 = ((3 + js) & 3) << 2;

    float acc[2][16];
#pragma unroll
    for (int rr = 0; rr < 2; ++rr)
#pragma unroll
        for (int j = 0; j < 16; ++j) acc[rr][j] = 0.0f;

#define GLOAD(P, I) ((P) ? *(const float4*)((I)) : float4{0, 0, 0, 0})

// one 32-k tile's FMA block for tile index I using x-regs XV0/XV1
#define GCOMP(I, XV0, XV1)                                                      \
    {                                                                           \
        const float* base_ = &sW[((I) * 8 + o) * 64];                           \
        _Pragma("unroll")                                                       \
        for (int kk = 0; kk < 4; ++kk) {                                        \
            const float* wr = base_ + ((kk ^ klx) << 4);                        \
            float4 w0 = *(const float4*)(wr + rof0);                            \
            float4 w1 = *(const float4*)(wr + rof1);                            \
            float4 w2 = *(const float4*)(wr + rof2);                            \
            float4 w3 = *(const float4*)(wr + rof3);                            \
            float xs0 = (&(XV0).x)[kk], xs1 = (&(XV1).x)[kk];                   \
            acc[0][0]  = fmaf(xs0, w0.x, acc[0][0]);   acc[1][0]  = fmaf(xs1, w0.x, acc[1][0]);  \
            acc[0][1]  = fmaf(xs0, w0.y, acc[0][1]);   acc[1][1]  = fmaf(xs1, w0.y, acc[1][1]);  \
            acc[0][2]  = fmaf(xs0, w0.z, acc[0][2]);   acc[1][2]  = fmaf(xs1, w0.z, acc[1][2]);  \
            acc[0][3]  = fmaf(xs0, w0.w, acc[0][3]);   acc[1][3]  = fmaf(xs1, w0.w, acc[1][3]);  \
            acc[0][4]  = fmaf(xs0, w1.x, acc[0][4]);   acc[1][4]  = fmaf(xs1, w1.x, acc[1][4]);  \
            acc[0][5]  = fmaf(xs0, w1.y, acc[0][5]);   acc[1][5]  = fmaf(xs1, w1.y, acc[1][5]);  \
            acc[0][6]  = fmaf(xs0, w1.z, acc[0][6]);   acc[1][6]  = fmaf(xs1, w1.z, acc[1][6]);  \
            acc[0][7]  = fmaf(xs0, w1.w, acc[0][7]);   acc[1][7]  = fmaf(xs1, w1.w, acc[1][7]);  \
            acc[0][8]  = fmaf(xs0, w2.x, acc[0][8]);   acc[1][8]  = fmaf(xs1, w2.x, acc[1][8]);  \
            acc[0][9]  = fmaf(xs0, w2.y, acc[0][9]);   acc[1][9]  = fmaf(xs1, w2.y, acc[1][9]);  \
            acc[0][10] = fmaf(xs0, w2.z, acc[0][10]);  acc[1][10] = fmaf(xs1, w2.z, acc[1][10]); \
            acc[0][11] = fmaf(xs0, w2.w, acc[0][11]);  acc[1][11] = fmaf(xs1, w2.w, acc[1][11]); \
            acc[0][12] = fmaf(xs0, w3.x, acc[0][12]);  acc[1][12] = fmaf(xs1, w3.x, acc[1][12]); \
            acc[0][13] = fmaf(xs0, w3.y, acc[0][13]);  acc[1][13] = fmaf(xs1, w3.y, acc[1][13]); \
            acc[0][14] = fmaf(xs0, w3.z, acc[0][14]);  acc[1][14] = fmaf(xs1, w3.z, acc[1][14]); \
            acc[0][15] = fmaf(xs0, w3.w, acc[0][15]);  acc[1][15] = fmaf(xs1, w3.w, acc[1][15]); \
        }                                                                       \
    }

    // software pipeline, depth 2: slots A (even tiles) and B (odd tiles)
    float4 pa0 = GLOAD(ok0, x0 + 0 * 32 + o * 4);
    float4 pa1 = GLOAD(ok1, x1 + 0 * 32 + o * 4);
    float4 pb0 = GLOAD(ok0, x0 + 1 * 32 + o * 4);
    float4 pb1 = GLOAD(ok1, x1 + 1 * 32 + o * 4);

#pragma unroll
    for (int i = 0; i < 16; i += 2) {
        float4 ca0 = pa0, ca1 = pa1;
        if (i + 2 < 16) {                       // issue tile i+2 (slot A)
            pa0 = GLOAD(ok0, x0 + (i + 2) * 32 + o * 4);
            pa1 = GLOAD(ok1, x1 + (i + 2) * 32 + o * 4);
        }
        GCOMP(i, ca0, ca1);
        float4 cb0 = pb0, cb1 = pb1;
        if (i + 3 < 16) {                       // issue tile i+3 (slot B)
            pb0 = GLOAD(ok0, x0 + (i + 3) * 32 + o * 4);
            pb1 = GLOAD(ok1, x1 + (i + 3) * 32 + o * 4);
        }
        GCOMP(i + 1, cb0, cb1);
    }
#undef GCOMP
#undef GLOAD

    // reduce-scatter over the 8 lanes: lane o ends holding j in {2o, 2o+1}
#pragma unroll
    for (int rr = 0; rr < 2; ++rr) {
        float t16[16];
#pragma unroll
        for (int j = 0; j < 16; ++j)
            t16[j] = acc[rr][j] + __shfl_xor(acc[rr][j], 4);
        float k8[8];
#pragma unroll
        for (int j = 0; j < 8; ++j)
            k8[j] = (o & 4) ? t16[8 + j] : t16[j];
        float t8[8];
#pragma unroll
        for (int j = 0; j < 8; ++j)
            t8[j] = k8[j] + __shfl_xor(k8[j], 2);
        float k4[4];
#pragma unroll
        for (int j = 0; j < 4; ++j)
            k4[j] = (o & 2) ? t8[4 + j] : t8[j];
        float t4[4];
#pragma unroll
        for (int j = 0; j < 4; ++j)
            t4[j] = k4[j] + __shfl_xor(k4[j], 1);
        acc[rr][0] = (o & 1) ? t4[2] : t4[0];
        acc[rr][1] = (o & 1) ? t4[3] : t4[1];
    }

    if (ok0) {
        *(float2*)(h1s + (size_t)row0 * HIDDEN + o * 2) =
            float2{acc[0][0] * d0, acc[0][1] * d0};
    }
    if (ok1) {
        *(float2*)(h1s + (size_t)row1 * HIDDEN + o * 2) =
            float2{acc[1][0] * d1, acc[1][1] * d1};
    }
}

// ---- agg layer 1: g = relu(dis*(self+Σ h1s[r]) + b1) * dis ----
// 4 lanes per node; coalesced csr reads + shfl broadcast; 4 gathers in flight.
__global__ __launch_bounds__(256) void k_agg1(
        const int* __restrict__ offsets, const int* __restrict__ cnt,
        const int* __restrict__ csr, const float* __restrict__ dis,
        const float* __restrict__ b1,
        const float* __restrict__ h1s, float* __restrict__ g) {
    int t = blockIdx.x * 256 + threadIdx.x;
    int node = t >> 2;
    if (node >= N_NODES) return;          // quad-uniform exit: shfl sources stay active
    int q = t & 3;
    int lanebase = (threadIdx.x & 63) & ~3;

    float4 acc = *(const float4*)(h1s + (size_t)node * HIDDEN + q * 4);  // self
    int start = offsets[node];
    int n = cnt[node];
    int i = 0;
    for (; i + 4 <= n; i += 4) {
        int rv = csr[start + i + q];      // coalesced across the quad
#pragma unroll
        for (int j = 0; j < 4; ++j) {
            int r = __shfl(rv, lanebase + j);
            float4 v = *(const float4*)(h1s + (size_t)r * HIDDEN + q * 4);
            acc.x += v.x; acc.y += v.y; acc.z += v.z; acc.w += v.w;
        }
    }
    for (; i < n; ++i) {
        int r = csr[start + i];           // same addr in quad: broadcast
        float4 v = *(const float4*)(h1s + (size_t)r * HIDDEN + q * 4);
        acc.x += v.x; acc.y += v.y; acc.z += v.z; acc.w += v.w;
    }
    float d = dis[node];
    float4 bq = *(const float4*)(b1 + q * 4);
    float4 r;
    r.x = fmaxf(fmaf(acc.x, d, bq.x), 0.0f) * d;
    r.y = fmaxf(fmaf(acc.y, d, bq.y), 0.0f) * d;
    r.z = fmaxf(fmaf(acc.z, d, bq.z), 0.0f) * d;
    r.w = fmaxf(fmaf(acc.w, d, bq.w), 0.0f) * d;
    *(float4*)(g + (size_t)node * HIDDEN + q * 4) = r;
}

// ---- agg layer 2: out = b2 + (dis*(self+Σ g[r])) @ W2 ----
__global__ __launch_bounds__(256) void k_agg2(
        const int* __restrict__ offsets, const int* __restrict__ cnt,
        const int* __restrict__ csr, const float* __restrict__ dis,
        const float* __restrict__ W2, const float* __restrict__ b2,
        const float* __restrict__ g, float* __restrict__ out) {
    __shared__ float sW[HIDDEN * N_CLS];
    __shared__ float sb2[N_CLS];
    __shared__ float sAgg[64][HIDDEN + 1];
    int t = threadIdx.x;
    for (int i = t; i < HIDDEN * N_CLS; i += 256) sW[i] = W2[i];
    if (t < N_CLS) sb2[t] = b2[t];

    int gt = blockIdx.x * 256 + t;
    int node = gt >> 2;
    int q = t & 3;
    int ln = t >> 2;
    int lanebase = (t & 63) & ~3;

    if (node < N_NODES) {
        float4 acc = *(const float4*)(g + (size_t)node * HIDDEN + q * 4);  // self
        int start = offsets[node];
        int n = cnt[node];
        int i = 0;
        for (; i + 4 <= n; i += 4) {
            int rv = csr[start + i + q];
#pragma unroll
            for (int j = 0; j < 4; ++j) {
                int r = __shfl(rv, lanebase + j);
                float4 v = *(const float4*)(g + (size_t)r * HIDDEN + q * 4);
                acc.x += v.x; acc.y += v.y; acc.z += v.z; acc.w += v.w;
            }
        }
        for (; i < n; ++i) {
            int r = csr[start + i];
            float4 v = *(const float4*)(g + (size_t)r * HIDDEN + q * 4);
            acc.x += v.x; acc.y += v.y; acc.z += v.z; acc.w += v.w;
        }
        float d = dis[node];
        sAgg[ln][q*4+0] = acc.x * d;
        sAgg[ln][q*4+1] = acc.y * d;
        sAgg[ln][q*4+2] = acc.z * d;
        sAgg[ln][q*4+3] = acc.w * d;
    }
    __syncthreads();
    if (node >= N_NODES) return;

    float a[HIDDEN];
#pragma unroll
    for (int j = 0; j < HIDDEN; ++j) a[j] = sAgg[ln][j];

    int c0 = q * 10;
    float o[10];
#pragma unroll
    for (int k = 0; k < 10; ++k) o[k] = sb2[c0 + k];
#pragma unroll
    for (int j = 0; j < HIDDEN; ++j) {
        float aj = a[j];
        const float* wr = &sW[j * N_CLS + c0];
#pragma unroll
        for (int k = 0; k < 10; ++k) o[k] = fmaf(aj, wr[k], o[k]);
    }
    float* op = out + (size_t)node * N_CLS + c0;
#pragma unroll
    for (int k = 0; k < 10; ++k) op[k] = o[k];
}

extern "C" void kernel_launch(void* const* d_in, const int* in_sizes, int n_in,
                              void* d_out, int out_size, void* d_ws, size_t ws_size,
                              hipStream_t stream) {
    const float* x  = (const float*)d_in[0];
    const int*   ei = (const int*)d_in[1];
    const float* W1 = (const float*)d_in[2];
    const float* b1 = (const float*)d_in[3];
    const float* W2 = (const float*)d_in[4];
    const float* b2 = (const float*)d_in[5];
    float* out = (float*)d_out;

    // ws: bucketCnt[784] | boff[784] | cur[784] | offsets[N] | cnt[N] | dis[N] |
    //     binned[E] | csr[E] | h1s[N*16] | g[N*16]   ≈ 27 MB
    char* w = (char*)d_ws;
    int*   bucketCnt = (int*)w;    w += 784 * 4;
    int*   boff      = (int*)w;    w += 784 * 4;
    int*   cur       = (int*)w;    w += 784 * 4;
    int*   offsets   = (int*)w;    w += (size_t)N_NODES * 4;
    int*   cnt       = (int*)w;    w += (size_t)N_NODES * 4;
    float* dis       = (float*)w;  w += (size_t)N_NODES * 4;
    int*   binned    = (int*)w;    w += (size_t)N_EDGES * 4;
    int*   csr       = (int*)w;    w += (size_t)N_EDGES * 4;
    float* h1s       = (float*)w;  w += (size_t)N_NODES * HIDDEN * 4;
    float* g         = (float*)w;

    const int gGemm = (N_NODES + 63) / 64;         // 1563
    const int gAgg  = (N_NODES * 4 + 255) / 256;   // 1563

    k_zero <<<(NB + 255) / 256, 256, 0, stream>>>(bucketCnt, NB);
    k_binc <<<NWGBIN, 256, 0, stream>>>(ei, bucketCnt);
    k_bscan<<<1, 1024, 0, stream>>>(bucketCnt, boff, cur);
    k_bfill<<<NWGBIN, 256, 0, stream>>>(ei, cur, binned);
    k_csr  <<<NB, 256, 0, stream>>>(boff, binned, csr, offsets, cnt, dis);
    k_gemm1<<<gGemm, 256, 0, stream>>>(x, W1, dis, h1s);
    k_agg1 <<<gAgg, 256, 0, stream>>>(offsets, cnt, csr, dis, b1, h1s, g);
    k_agg2 <<<gAgg, 256, 0, stream>>>(offsets, cnt, csr, dis, W2, b2, g, out);
}

// Round 5
// 421.336 us; speedup vs baseline: 2.1921x; 2.1921x over previous
//
#include <hip/hip_runtime.h>

#define N_NODES 100000
#define N_EDGES 1600000
#define F_IN    512
#define HIDDEN  16
#define N_CLS   40

#define BSHIFT  7
#define BSIZE   128                                // nodes per bucket
#define NB      ((N_NODES + BSIZE - 1) / BSIZE)    // 782 buckets
#define NWGBIN  256
#define CHUNK   (N_EDGES / NWGBIN)                 // 6250 (exact)

static_assert(N_EDGES % NWGBIN == 0, "chunking must be exact");

typedef __attribute__((ext_vector_type(8))) short bf16x8;
typedef __attribute__((ext_vector_type(4))) float f32x4;

// ---------------- zero bucket counters ----------------
__global__ void k_zero(int* __restrict__ p, int n) {
    int i = blockIdx.x * blockDim.x + threadIdx.x;
    if (i < n) p[i] = 0;
}

// ---------------- pass A: per-bucket edge counts ----------------
__global__ __launch_bounds__(256) void k_binc(const int* __restrict__ ei,
                                              int* __restrict__ bucketCnt) {
    __shared__ int h[NB];
    int t = threadIdx.x;
    for (int b = t; b < NB; b += 256) h[b] = 0;
    __syncthreads();
    int start = blockIdx.x * CHUNK, end = start + CHUNK;
    for (int e = start + t; e < end; e += 256)
        atomicAdd(&h[ei[N_EDGES + e] >> BSHIFT], 1);
    __syncthreads();
    for (int b = t; b < NB; b += 256)
        if (h[b]) atomicAdd(&bucketCnt[b], h[b]);
}

// ---------------- exclusive scan of 782 bucket counts ----------------
__global__ __launch_bounds__(1024) void k_bscan(const int* __restrict__ bucketCnt,
                                                int* __restrict__ boff,
                                                int* __restrict__ cur) {
    __shared__ int s[1024];
    int t = threadIdx.x;
    int v = (t < NB) ? bucketCnt[t] : 0;
    s[t] = v; __syncthreads();
    for (int o = 1; o < 1024; o <<= 1) {
        int add = (t >= o) ? s[t - o] : 0;
        __syncthreads();
        s[t] += add;
        __syncthreads();
    }
    if (t < NB) { int ex = s[t] - v; boff[t] = ex; cur[t] = ex; }
    if (t == 0) boff[NB] = N_EDGES;
}

// ---------------- pass B: place packed edges (r | lc<<17) ----------------
__global__ __launch_bounds__(256) void k_bfill(const int* __restrict__ ei,
                                               int* __restrict__ cur,
                                               int* __restrict__ binned) {
    __shared__ int lc[NB];
    int t = threadIdx.x;
    int start = blockIdx.x * CHUNK, end = start + CHUNK;
    for (int b = t; b < NB; b += 256) lc[b] = 0;
    __syncthreads();
    for (int e = start + t; e < end; e += 256)
        atomicAdd(&lc[ei[N_EDGES + e] >> BSHIFT], 1);
    __syncthreads();
    for (int b = t; b < NB; b += 256) {
        int c = lc[b];
        lc[b] = c ? atomicAdd(&cur[b], c) : 0;
    }
    __syncthreads();
    for (int e = start + t; e < end; e += 256) {
        int r = ei[e], c = ei[N_EDGES + e];
        int b = c >> BSHIFT;
        int pos = atomicAdd(&lc[b], 1);
        binned[pos] = r | ((c & (BSIZE - 1)) << 17);
    }
}

// ------ per-bucket counting sort: binned -> node-sorted csr + offsets/cnt/dis ----
__global__ __launch_bounds__(256) void k_csr(const int* __restrict__ boff,
                                             const int* __restrict__ binned,
                                             int* __restrict__ csr,
                                             int* __restrict__ offsets,
                                             int* __restrict__ cnt,
                                             float* __restrict__ dis) {
    __shared__ int h[BSIZE];      // per-local-node histogram
    __shared__ int sc[BSIZE];     // scan
    __shared__ int curL[BSIZE];   // local cursors (absolute csr positions)
    int t = threadIdx.x, b = blockIdx.x;
    if (t < BSIZE) h[t] = 0;
    __syncthreads();
    int s = boff[b], e = boff[b + 1];
    for (int i = s + t; i < e; i += 256)
        atomicAdd(&h[binned[i] >> 17], 1);
    __syncthreads();
    int v = (t < BSIZE) ? h[t] : 0;
    if (t < BSIZE) sc[t] = v;
    __syncthreads();
    for (int o = 1; o < BSIZE; o <<= 1) {
        int add = (t < BSIZE && t >= o) ? sc[t - o] : 0;
        __syncthreads();
        if (t < BSIZE) sc[t] += add;
        __syncthreads();
    }
    if (t < BSIZE) {
        int ex = s + sc[t] - v;           // absolute exclusive offset
        curL[t] = ex;
        int node = b * BSIZE + t;
        if (node < N_NODES) {
            offsets[node] = ex;
            cnt[node]     = v;
            dis[node]     = rsqrtf(1.0f + (float)v);
        }
    }
    __syncthreads();
    for (int i = s + t; i < e; i += 256) {
        int p = binned[i];
        int pos = atomicAdd(&curL[p >> 17], 1);
        csr[pos] = p & 0x1FFFF;
    }
}

// ---------------- layer-1 GEMM (MFMA): h1s = (x @ W1) * dis ----------------
// bf16-split for fp32 accuracy: x = xh + xl, W = Wh + Wl (bf16 each);
// acc = xh*Wh + xh*Wl + xl*Wh  (xl*Wl ~ 2^-16, dropped).
// One wave owns a 16-row block (M=16, N=16=HIDDEN, K=512 in 16 k-tiles of 32).
// mfma_f32_16x16x32_bf16: A lane l holds x[row0+(l&15)][kt*32+(l>>4)*8 ..+7];
// B lane l holds W[kt*32+(l>>4)*8 ..+7][l&15]; D: m=(l>>4)*4+r, n=l&15 (m89).
// W staged transposed in LDS, bf16 hi/lo, XOR-swizzled (idx ^ (n&7)<<3) so
// the wave's b128 B-frag reads spread uniformly over all 32 banks.
// 32 KiB LDS/WG, 4 waves/WG -> 5 WG/CU; per-wave chain is 10x shorter than
// the old VALU version (48 MFMA replace 32K lane-FMAs) -> pure x-stream.
__global__ __launch_bounds__(256) void k_gemm1(
        const float* __restrict__ x, const float* __restrict__ W1,
        const float* __restrict__ dis, float* __restrict__ h1s) {
    __shared__ short sWhi[F_IN * HIDDEN];   // 16 KiB
    __shared__ short sWlo[F_IN * HIDDEN];   // 16 KiB
    int t = threadIdx.x;
    for (int idx = t; idx < F_IN * HIDDEN; idx += 256) {
        int k = idx >> 4, n = idx & 15;
        float f = W1[idx];
        unsigned u  = __float_as_uint(f);
        unsigned rh = u + 0x7FFFu + ((u >> 16) & 1u);     // RNE to bf16
        float fh = __uint_as_float(rh & 0xFFFF0000u);
        float fl = f - fh;                                 // exact
        unsigned v  = __float_as_uint(fl);
        unsigned rl = v + 0x7FFFu + ((v >> 16) & 1u);
        int p = (n * F_IN + k) ^ ((n & 7) << 3);           // swizzled short-index
        sWhi[p] = (short)(rh >> 16);
        sWlo[p] = (short)(rl >> 16);
    }
    __syncthreads();

    int bid = blockIdx.x * 4 + (t >> 6);       // 16-row block id
    if (bid >= N_NODES / 16) return;           // after barrier: safe
    int l  = t & 63;
    int n  = l & 15;                           // A row lane / B col lane / D col
    int ko = (l >> 4) << 3;                    // k-octet within a 32-k tile
    const float* xp = x + (size_t)(bid * 16 + n) * F_IN + ko;
    const int xsw = (n & 7) << 3;
    const int nb  = n * F_IN;

    f32x4 accA = {0.f, 0.f, 0.f, 0.f};
    f32x4 accB = {0.f, 0.f, 0.f, 0.f};

    // depth-2 rotating prefetch (all indices compile-time after full unroll)
    float4 pA0 = *(const float4*)(xp + 0);
    float4 pB0 = *(const float4*)(xp + 4);
    float4 pA1 = *(const float4*)(xp + 32);
    float4 pB1 = *(const float4*)(xp + 36);

#pragma unroll
    for (int kt = 0; kt < 16; ++kt) {
        float4 a = (kt & 1) ? pA1 : pA0;
        float4 b = (kt & 1) ? pB1 : pB0;
        if (kt + 2 < 16) {
            const float4* src0 = (const float4*)(xp + (kt + 2) * 32);
            const float4* src1 = (const float4*)(xp + (kt + 2) * 32 + 4);
            if (kt & 1) { pA1 = *src0; pB1 = *src1; }
            else        { pA0 = *src0; pB0 = *src1; }
        }
        float fs[8] = {a.x, a.y, a.z, a.w, b.x, b.y, b.z, b.w};
        bf16x8 ah, al;
#pragma unroll
        for (int e = 0; e < 8; ++e) {
            unsigned u  = __float_as_uint(fs[e]);
            unsigned rh = u + 0x7FFFu + ((u >> 16) & 1u);
            ah[e] = (short)(rh >> 16);
            float fl = fs[e] - __uint_as_float(rh & 0xFFFF0000u);
            unsigned v  = __float_as_uint(fl);
            unsigned rl = v + 0x7FFFu + ((v >> 16) & 1u);
            al[e] = (short)(rl >> 16);
        }
        int p = (nb + kt * 32 + ko) ^ xsw;
        bf16x8 bh = *(const bf16x8*)(sWhi + p);
        bf16x8 bl = *(const bf16x8*)(sWlo + p);
        accA = __builtin_amdgcn_mfma_f32_16x16x32_bf16(ah, bh, accA, 0, 0, 0);
        accB = __builtin_amdgcn_mfma_f32_16x16x32_bf16(ah, bl, accB, 0, 0, 0);
        accB = __builtin_amdgcn_mfma_f32_16x16x32_bf16(al, bh, accB, 0, 0, 0);
    }

    // D: m = (l>>4)*4 + r, col n = l&15 (guide-verified C/D layout)
    int mrow = bid * 16 + ((l >> 4) << 2);
#pragma unroll
    for (int r = 0; r < 4; ++r) {
        float d = dis[mrow + r];
        h1s[(size_t)(mrow + r) * HIDDEN + n] = (accA[r] + accB[r]) * d;
    }
}

// ---- agg layer 1: g = relu(dis*(self+Σ h1s[r]) + b1) * dis ----
// 4 lanes per node; coalesced csr reads + shfl broadcast; 4 gathers in flight.
__global__ __launch_bounds__(256) void k_agg1(
        const int* __restrict__ offsets, const int* __restrict__ cnt,
        const int* __restrict__ csr, const float* __restrict__ dis,
        const float* __restrict__ b1,
        const float* __restrict__ h1s, float* __restrict__ g) {
    int t = blockIdx.x * 256 + threadIdx.x;
    int node = t >> 2;
    if (node >= N_NODES) return;          // quad-uniform exit: shfl sources stay active
    int q = t & 3;
    int lanebase = (threadIdx.x & 63) & ~3;

    float4 acc = *(const float4*)(h1s + (size_t)node * HIDDEN + q * 4);  // self
    int start = offsets[node];
    int n = cnt[node];
    int i = 0;
    for (; i + 4 <= n; i += 4) {
        int rv = csr[start + i + q];      // coalesced across the quad
#pragma unroll
        for (int j = 0; j < 4; ++j) {
            int r = __shfl(rv, lanebase + j);
            float4 v = *(const float4*)(h1s + (size_t)r * HIDDEN + q * 4);
            acc.x += v.x; acc.y += v.y; acc.z += v.z; acc.w += v.w;
        }
    }
    for (; i < n; ++i) {
        int r = csr[start + i];           // same addr in quad: broadcast
        float4 v = *(const float4*)(h1s + (size_t)r * HIDDEN + q * 4);
        acc.x += v.x; acc.y += v.y; acc.z += v.z; acc.w += v.w;
    }
    float d = dis[node];
    float4 bq = *(const float4*)(b1 + q * 4);
    float4 r;
    r.x = fmaxf(fmaf(acc.x, d, bq.x), 0.0f) * d;
    r.y = fmaxf(fmaf(acc.y, d, bq.y), 0.0f) * d;
    r.z = fmaxf(fmaf(acc.z, d, bq.z), 0.0f) * d;
    r.w = fmaxf(fmaf(acc.w, d, bq.w), 0.0f) * d;
    *(float4*)(g + (size_t)node * HIDDEN + q * 4) = r;
}

// ---- agg layer 2: out = b2 + (dis*(self+Σ g[r])) @ W2 ----
__global__ __launch_bounds__(256) void k_agg2(
        const int* __restrict__ offsets, const int* __restrict__ cnt,
        const int* __restrict__ csr, const float* __restrict__ dis,
        const float* __restrict__ W2, const float* __restrict__ b2,
        const float* __restrict__ g, float* __restrict__ out) {
    __shared__ float sW[HIDDEN * N_CLS];
    __shared__ float sb2[N_CLS];
    __shared__ float sAgg[64][HIDDEN + 1];
    int t = threadIdx.x;
    for (int i = t; i < HIDDEN * N_CLS; i += 256) sW[i] = W2[i];
    if (t < N_CLS) sb2[t] = b2[t];

    int gt = blockIdx.x * 256 + t;
    int node = gt >> 2;
    int q = t & 3;
    int ln = t >> 2;
    int lanebase = (t & 63) & ~3;

    if (node < N_NODES) {
        float4 acc = *(const float4*)(g + (size_t)node * HIDDEN + q * 4);  // self
        int start = offsets[node];
        int n = cnt[node];
        int i = 0;
        for (; i + 4 <= n; i += 4) {
            int rv = csr[start + i + q];
#pragma unroll
            for (int j = 0; j < 4; ++j) {
                int r = __shfl(rv, lanebase + j);
                float4 v = *(const float4*)(g + (size_t)r * HIDDEN + q * 4);
                acc.x += v.x; acc.y += v.y; acc.z += v.z; acc.w += v.w;
            }
        }
        for (; i < n; ++i) {
            int r = csr[start + i];
            float4 v = *(const float4*)(g + (size_t)r * HIDDEN + q * 4);
            acc.x += v.x; acc.y += v.y; acc.z += v.z; acc.w += v.w;
        }
        float d = dis[node];
        sAgg[ln][q*4+0] = acc.x * d;
        sAgg[ln][q*4+1] = acc.y * d;
        sAgg[ln][q*4+2] = acc.z * d;
        sAgg[ln][q*4+3] = acc.w * d;
    }
    __syncthreads();
    if (node >= N_NODES) return;

    float a[HIDDEN];
#pragma unroll
    for (int j = 0; j < HIDDEN; ++j) a[j] = sAgg[ln][j];

    int c0 = q * 10;
    float o[10];
#pragma unroll
    for (int k = 0; k < 10; ++k) o[k] = sb2[c0 + k];
#pragma unroll
    for (int j = 0; j < HIDDEN; ++j) {
        float aj = a[j];
        const float* wr = &sW[j * N_CLS + c0];
#pragma unroll
        for (int k = 0; k < 10; ++k) o[k] = fmaf(aj, wr[k], o[k]);
    }
    float* op = out + (size_t)node * N_CLS + c0;
#pragma unroll
    for (int k = 0; k < 10; ++k) op[k] = o[k];
}

extern "C" void kernel_launch(void* const* d_in, const int* in_sizes, int n_in,
                              void* d_out, int out_size, void* d_ws, size_t ws_size,
                              hipStream_t stream) {
    const float* x  = (const float*)d_in[0];
    const int*   ei = (const int*)d_in[1];
    const float* W1 = (const float*)d_in[2];
    const float* b1 = (const float*)d_in[3];
    const float* W2 = (const float*)d_in[4];
    const float* b2 = (const float*)d_in[5];
    float* out = (float*)d_out;

    // ws: bucketCnt[784] | boff[784] | cur[784] | offsets[N] | cnt[N] | dis[N] |
    //     binned[E] | csr[E] | h1s[N*16] | g[N*16]   ≈ 27 MB
    char* w = (char*)d_ws;
    int*   bucketCnt = (int*)w;    w += 784 * 4;
    int*   boff      = (int*)w;    w += 784 * 4;
    int*   cur       = (int*)w;    w += 784 * 4;
    int*   offsets   = (int*)w;    w += (size_t)N_NODES * 4;
    int*   cnt       = (int*)w;    w += (size_t)N_NODES * 4;
    float* dis       = (float*)w;  w += (size_t)N_NODES * 4;
    int*   binned    = (int*)w;    w += (size_t)N_EDGES * 4;
    int*   csr       = (int*)w;    w += (size_t)N_EDGES * 4;
    float* h1s       = (float*)w;  w += (size_t)N_NODES * HIDDEN * 4;
    float* g         = (float*)w;

    const int gGemm = (N_NODES / 16 + 3) / 4;      // 6250 blocks / 4 waves = 1563
    const int gAgg  = (N_NODES * 4 + 255) / 256;   // 1563

    k_zero <<<(NB + 255) / 256, 256, 0, stream>>>(bucketCnt, NB);
    k_binc <<<NWGBIN, 256, 0, stream>>>(ei, bucketCnt);
    k_bscan<<<1, 1024, 0, stream>>>(bucketCnt, boff, cur);
    k_bfill<<<NWGBIN, 256, 0, stream>>>(ei, cur, binned);
    k_csr  <<<NB, 256, 0, stream>>>(boff, binned, csr, offsets, cnt, dis);
    k_gemm1<<<gGemm, 256, 0, stream>>>(x, W1, dis, h1s);
    k_agg1 <<<gAgg, 256, 0, stream>>>(offsets, cnt, csr, dis, b1, h1s, g);
    k_agg2 <<<gAgg, 256, 0, stream>>>(offsets, cnt, csr, dis, W2, b2, g, out);
}